// Round 3
// baseline (3513.560 us; speedup 1.0000x reference)
//
#include <hip/hip_runtime.h>
#include <hip/hip_bf16.h>

constexpr int NNODES = 25000;
constexpr int NEDGES = 400000;
constexpr int DD = 64;
constexpr float BNEPS = 1e-5f;
constexpr float AGGEPS = 1e-6f;

// storage-type helpers (compute is always fp32)
__device__ __forceinline__ float ldv(const float* p, long i) { return p[i]; }
__device__ __forceinline__ float ldv(const __hip_bfloat16* p, long i) { return __bfloat162float(p[i]); }
__device__ __forceinline__ void stv(float* p, long i, float v) { p[i] = v; }
__device__ __forceinline__ void stv(__hip_bfloat16* p, long i, float v) { p[i] = __float2bfloat16(v); }

// ---------------------------------------------------------------------------
// Generic LDS-tiled linear: Y[r][n] (+)= bias[n] + sum_k X[g(r)][k] * W[k][n]
// ---------------------------------------------------------------------------
template<int K, int N, int JR, bool RELU, typename TX, typename TY>
__global__ __launch_bounds__(256) void linear_kernel(
    const TX* __restrict__ X, const float* __restrict__ W,
    const float* __restrict__ Bb, TY* __restrict__ Y,
    int rows)
{
    constexpr int SLOTS = 256 / N;
    constexpr int RPG = SLOTS * JR;   // rows per group
    __shared__ float wl[K * N];
    __shared__ float bl[N];
    __shared__ float xl[RPG * K];

    const int tid = threadIdx.x;
    for (int i = tid; i < K * N; i += 256) wl[i] = W[i];
    if (tid < N) bl[tid] = Bb ? Bb[tid] : 0.0f;

    const int col = tid % N;
    const int slot = tid / N;

    const int ngroups = (rows + RPG - 1) / RPG;
    for (int g = blockIdx.x; g < ngroups; g += gridDim.x) {
        const int rowBase = g * RPG;
        __syncthreads();
        for (int i = tid; i < RPG * K; i += 256) {
            int r = i / K, k = i - r * K;
            int row = rowBase + r;
            xl[i] = (row < rows) ? ldv(X, (long)row * K + k) : 0.0f;
        }
        __syncthreads();
        float acc[JR];
        #pragma unroll
        for (int j = 0; j < JR; ++j) acc[j] = bl[col];
        #pragma unroll 4
        for (int k = 0; k < K; ++k) {
            float w = wl[k * N + col];
            #pragma unroll
            for (int j = 0; j < JR; ++j)
                acc[j] += xl[(slot * JR + j) * K + k] * w;
        }
        #pragma unroll
        for (int j = 0; j < JR; ++j) {
            int row = rowBase + slot * JR + j;
            if (row < rows) {
                float v = acc[j];
                if (RELU) v = fmaxf(v, 0.0f);
                stv(Y, (long)row * N + col, v);
            }
        }
    }
}

// e_hat[i][c] += Dh[src[i]][c] + Eh[dst[i]][c]
template<typename TH>
__global__ __launch_bounds__(256) void gather_add2_kernel(
    TH* __restrict__ ehat, const float* __restrict__ Dh,
    const int* __restrict__ src, const float* __restrict__ Eh,
    const int* __restrict__ dst, int rows)
{
    long total = (long)rows * DD;
    for (long gid = (long)blockIdx.x * 256 + threadIdx.x; gid < total;
         gid += (long)gridDim.x * 256) {
        int i = (int)(gid >> 6), c = (int)(gid & 63);
        int s = src[i], d = dst[i];
        float v = ldv(ehat, gid) + Dh[(long)s * DD + c] + Eh[(long)d * DD + c];
        stv(ehat, gid, v);
    }
}

// num[dst][c] += sig*Bh[src][c] ; den[dst][c] += sig
template<typename TH>
__global__ __launch_bounds__(256) void aggregate_kernel(
    const TH* __restrict__ ehat, const float* __restrict__ Bh,
    const int* __restrict__ src, const int* __restrict__ dst,
    float* __restrict__ num, float* __restrict__ den, int rows)
{
    long total = (long)rows * DD;
    for (long gid = (long)blockIdx.x * 256 + threadIdx.x; gid < total;
         gid += (long)gridDim.x * 256) {
        int i = (int)(gid >> 6), c = (int)(gid & 63);
        float s = 1.0f / (1.0f + __expf(-ldv(ehat, gid)));
        int sr = src[i], d = dst[i];
        atomicAdd(&den[(long)d * DD + c], s);
        atomicAdd(&num[(long)d * DD + c], s * Bh[(long)sr * DD + c]);
    }
}

// hhat = Ah + num/(den+eps)
__global__ __launch_bounds__(256) void hhat_kernel(
    const float* __restrict__ Ah, const float* __restrict__ num,
    const float* __restrict__ den, float* __restrict__ hhat, long total)
{
    for (long gid = (long)blockIdx.x * 256 + threadIdx.x; gid < total;
         gid += (long)gridDim.x * 256)
        hhat[gid] = Ah[gid] + num[gid] / (den[gid] + AGGEPS);
}

// per-column sum & sumsq via block reduce + atomics (stats zeroed beforehand)
template<typename TX>
__global__ __launch_bounds__(256) void bn_stats_kernel(
    const TX* __restrict__ X, float* __restrict__ stats, int rows)
{
    __shared__ float sb[256], sb2[256];
    int tid = threadIdx.x;
    int c = tid & 63, slot = tid >> 6;
    float s = 0.0f, s2 = 0.0f;
    for (int r = blockIdx.x * 4 + slot; r < rows; r += gridDim.x * 4) {
        float x = ldv(X, (long)r * DD + c);
        s += x; s2 += x * x;
    }
    sb[tid] = s; sb2[tid] = s2;
    __syncthreads();
    if (tid < 64) {
        s  = sb[tid] + sb[tid + 64] + sb[tid + 128] + sb[tid + 192];
        s2 = sb2[tid] + sb2[tid + 64] + sb2[tid + 128] + sb2[tid + 192];
        atomicAdd(&stats[tid], s);
        atomicAdd(&stats[64 + tid], s2);
    }
}

// base += relu((xhat - mu)*rstd*g + b)
template<typename TB, typename TX>
__global__ __launch_bounds__(256) void bn_apply_kernel(
    TB* __restrict__ base, const TX* __restrict__ xhat,
    const float* __restrict__ stats, const float* __restrict__ g,
    const float* __restrict__ b, int rows)
{
    long total = (long)rows * DD;
    float inv = 1.0f / (float)rows;
    for (long gid = (long)blockIdx.x * 256 + threadIdx.x; gid < total;
         gid += (long)gridDim.x * 256) {
        int c = (int)(gid & 63);
        float mu = stats[c] * inv;
        float var = stats[64 + c] * inv - mu * mu;
        float rstd = rsqrtf(var + BNEPS);
        float v = (ldv(xhat, gid) - mu) * rstd * g[c] + b[c];
        stv(base, gid, ldv(base, gid) + fmaxf(v, 0.0f));
    }
}

// ---------------------------------------------------------------------------
// Fused MLP readout: out = relu(relu(feat@W0+b0)@W1+b1)@W2+b2 with
// feat = [e, e[rev], h[src], h[dst]]; nothing materialized to HBM.
// Tile = 32 edges/block. LDS: xs 8K + ws 32K + x0ls 16K + smallb = 57.3 KB.
// ---------------------------------------------------------------------------
template<typename TE>
__global__ __launch_bounds__(256) void readout_kernel(
    const TE* __restrict__ e, const float* __restrict__ h,
    const int* __restrict__ src, const int* __restrict__ dst,
    const int* __restrict__ rev,
    const float* __restrict__ W0, const float* __restrict__ b0,
    const float* __restrict__ W1, const float* __restrict__ b1,
    const float* __restrict__ W2, const float* __restrict__ b2,
    float* __restrict__ out, int rows)
{
    __shared__ float xs[32 * 64];     // feat slice tile
    __shared__ float ws[64 * 128];    // W0 slice (64x128) / W1 (128x64)
    __shared__ float x0ls[32 * 128];  // x0 tile; reused as x1 tile (32 x stride65)
    __shared__ float smallb[322];     // b0[128] | b1[64] | W2[128] | b2[2]

    const int tid = threadIdx.x;
    if (tid < 128) smallb[tid] = b0[tid];
    if (tid < 64)  smallb[128 + tid] = b1[tid];
    if (tid < 128) smallb[192 + tid] = W2[tid];
    if (tid < 2)   smallb[320 + tid] = b2[tid];

    const int col = tid & 127;   // x0 column
    const int rh  = tid >> 7;    // row half (0..1)
    const int col1 = tid & 63;   // x1 column
    const int rq   = tid >> 6;   // row quarter (0..3)

    const int ntiles = (rows + 31) / 32;
    for (int t = blockIdx.x; t < ntiles; t += gridDim.x) {
        const int rowBase = t * 32;
        float acc0[16];
        #pragma unroll
        for (int j = 0; j < 16; ++j) acc0[j] = 0.0f;

        for (int s = 0; s < 4; ++s) {
            __syncthreads();
            for (int i = tid; i < 32 * 64; i += 256) {
                int r = i >> 6, k = i & 63;
                int row = rowBase + r;
                float v = 0.0f;
                if (row < rows) {
                    if (s == 0)      v = ldv(e, (long)row * 64 + k);
                    else if (s == 1) v = ldv(e, (long)rev[row] * 64 + k);
                    else if (s == 2) v = h[(long)src[row] * 64 + k];
                    else             v = h[(long)dst[row] * 64 + k];
                }
                xs[i] = v;
            }
            for (int i = tid; i < 64 * 128; i += 256)
                ws[i] = W0[(long)s * 64 * 128 + i];
            __syncthreads();
            #pragma unroll 4
            for (int k = 0; k < 64; ++k) {
                float w = ws[k * 128 + col];
                #pragma unroll
                for (int j = 0; j < 16; ++j)
                    acc0[j] += xs[(rh * 16 + j) * 64 + k] * w;
            }
        }
        // x0 tile -> LDS (bias + relu)
        {
            float bb = smallb[col];
            #pragma unroll
            for (int j = 0; j < 16; ++j)
                x0ls[(rh * 16 + j) * 128 + col] = fmaxf(acc0[j] + bb, 0.0f);
        }
        __syncthreads();            // x0 visible; ws reads done
        for (int i = tid; i < 128 * 64; i += 256) ws[i] = W1[i];
        __syncthreads();
        // phase 2: x1 = relu(x0 @ W1 + b1)
        float acc1[8];
        {
            float bb = smallb[128 + col1];
            #pragma unroll
            for (int j = 0; j < 8; ++j) acc1[j] = bb;
        }
        #pragma unroll 4
        for (int k = 0; k < 128; ++k) {
            float w = ws[k * 64 + col1];
            #pragma unroll
            for (int j = 0; j < 8; ++j)
                acc1[j] += x0ls[(rq * 8 + j) * 128 + k] * w;
        }
        __syncthreads();            // x0 reads done; reuse region as x1 (stride 65)
        #pragma unroll
        for (int j = 0; j < 8; ++j)
            x0ls[(rq * 8 + j) * 65 + col1] = fmaxf(acc1[j], 0.0f);
        __syncthreads();
        // phase 3: out = x1 @ W2 + b2
        if (tid < 64) {
            int r = tid >> 1, cls = tid & 1;
            float a = smallb[320 + cls];
            #pragma unroll 8
            for (int k = 0; k < 64; ++k)
                a += x0ls[r * 65 + k] * smallb[192 + k * 2 + cls];
            int row = rowBase + r;
            if (row < rows) out[(long)row * 2 + cls] = a;
        }
    }
}

// ---------------------------------------------------------------------------
static inline int igrid(long total, int block, int cap) {
    long g = (total + block - 1) / block;
    return (int)(g < cap ? g : cap);
}

template<typename TE, typename TH>
static void run_net(void* const* d_in, float* f, TE* e, TH* ehat,
                    float* out, hipStream_t stream)
{
    const float* h_in   = (const float*)d_in[0];
    const float* e_in   = (const float*)d_in[1];
    const int*   src    = (const int*)d_in[2];
    const int*   dst    = (const int*)d_in[3];
    const int*   rev    = (const int*)d_in[4];
    const float* emb_h_w = (const float*)d_in[5];
    const float* emb_h_b = (const float*)d_in[6];
    const float* emb_e_w = (const float*)d_in[7];
    const float* emb_e_b = (const float*)d_in[8];
    const float* A_w = (const float*)d_in[9];  const float* A_b = (const float*)d_in[10];
    const float* B_w = (const float*)d_in[11]; const float* B_b = (const float*)d_in[12];
    const float* C_w = (const float*)d_in[13]; const float* C_b = (const float*)d_in[14];
    const float* D_w = (const float*)d_in[15]; const float* D_b = (const float*)d_in[16];
    const float* E_w = (const float*)d_in[17]; const float* E_b = (const float*)d_in[18];
    // F/G (19..22) and bn_u (27,28) are dead: u never reaches the output.
    const float* bn_h_g = (const float*)d_in[23]; const float* bn_h_b = (const float*)d_in[24];
    const float* bn_e_g = (const float*)d_in[25]; const float* bn_e_b = (const float*)d_in[26];
    const float* W0 = (const float*)d_in[29]; const float* b0 = (const float*)d_in[30];
    const float* W1 = (const float*)d_in[31]; const float* b1 = (const float*)d_in[32];
    const float* W2 = (const float*)d_in[33]; const float* b2 = (const float*)d_in[34];

    const size_t NH = (size_t)NNODES * DD;
    float* h    = f;
    float* Ah   = f + NH;
    float* Bh   = f + 2 * NH;
    float* Dh   = f + 3 * NH;      // hhat aliases Dh (Dh dead after gather_add2)
    float* Eh   = f + 4 * NH;
    float* num  = f + 5 * NH;
    float* den  = f + 6 * NH;
    float* stats= f + 7 * NH;      // 256 floats
    float* hhat = Dh;

    const int GE = 4096;
    const int GN = 1563;
    const int EW = igrid((long)NEDGES * DD, 256, 16384);
    const int NW = igrid((long)NNODES * DD, 256, 16384);

    // embeddings
    linear_kernel<64, 64, 4, false, float, float><<<GN, 256, 0, stream>>>(h_in, emb_h_w, emb_h_b, h, NNODES);
    linear_kernel<16, 64, 4, false, float, TE><<<GE, 256, 0, stream>>>(e_in, emb_e_w, emb_e_b, e, NEDGES);

    for (int l = 0; l < 4; ++l) {
        const float* Awl = A_w + (size_t)l * DD * DD; const float* Abl = A_b + l * DD;
        const float* Bwl = B_w + (size_t)l * DD * DD; const float* Bbl = B_b + l * DD;
        const float* Cwl = C_w + (size_t)l * DD * DD; const float* Cbl = C_b + l * DD;
        const float* Dwl = D_w + (size_t)l * DD * DD; const float* Dbl = D_b + l * DD;
        const float* Ewl = E_w + (size_t)l * DD * DD; const float* Ebl = E_b + l * DD;

        linear_kernel<64, 64, 4, false, float, float><<<GN, 256, 0, stream>>>(h, Awl, Abl, Ah, NNODES);
        linear_kernel<64, 64, 4, false, float, float><<<GN, 256, 0, stream>>>(h, Bwl, Bbl, Bh, NNODES);
        linear_kernel<64, 64, 4, false, float, float><<<GN, 256, 0, stream>>>(h, Dwl, Dbl, Dh, NNODES);
        linear_kernel<64, 64, 4, false, float, float><<<GN, 256, 0, stream>>>(h, Ewl, Ebl, Eh, NNODES);

        // e_hat = e@C + Cb + Dh[src] + Eh[dst]
        linear_kernel<64, 64, 4, false, TE, TH><<<GE, 256, 0, stream>>>(e, Cwl, Cbl, ehat, NEDGES);
        gather_add2_kernel<TH><<<EW, 256, 0, stream>>>(ehat, Dh, src, Eh, dst, NEDGES);

        // h_hat = Ah + sum(sig*Bh[src]) / (sum(sig)+eps)
        hipMemsetAsync(num, 0, 2 * NH * sizeof(float), stream);   // num+den contiguous
        aggregate_kernel<TH><<<EW, 256, 0, stream>>>(ehat, Bh, src, dst, num, den, NEDGES);
        hhat_kernel<<<NW, 256, 0, stream>>>(Ah, num, den, hhat, (long)NH);

        // BN + relu + residual (h then e)
        hipMemsetAsync(stats, 0, 256 * sizeof(float), stream);
        bn_stats_kernel<float><<<1024, 256, 0, stream>>>(hhat, stats, NNODES);
        bn_apply_kernel<float, float><<<NW, 256, 0, stream>>>(h, hhat, stats, bn_h_g + l * DD, bn_h_b + l * DD, NNODES);
        bn_stats_kernel<TH><<<1024, 256, 0, stream>>>(ehat, stats + 128, NEDGES);
        bn_apply_kernel<TE, TH><<<EW, 256, 0, stream>>>(e, ehat, stats + 128, bn_e_g + l * DD, bn_e_b + l * DD, NEDGES);
    }

    // fused MLP readout (no x0/x1 materialization)
    readout_kernel<TE><<<12500, 256, 0, stream>>>(e, h, src, dst, rev,
                                                  W0, b0, W1, b1, W2, b2,
                                                  (float*)out, NEDGES);
}

extern "C" void kernel_launch(void* const* d_in, const int* in_sizes, int n_in,
                              void* d_out, int out_size, void* d_ws, size_t ws_size,
                              hipStream_t stream)
{
    const size_t NH = (size_t)NNODES * DD;       // 1.6M floats
    const size_t NE = (size_t)NEDGES * DD;       // 25.6M elems
    const size_t baseB = (7 * NH + 256) * sizeof(float);   // 44.8 MB node region

    char* base = (char*)d_ws;
    char* edge = base + baseB;
    float* out = (float*)d_out;

    const size_t needA = baseB + NE * 4 * 2;          // fp32 e + fp32 ehat  (~249.6 MB)
    const size_t needB = baseB + NE * 4 + NE * 2;     // fp32 e + bf16 ehat  (~198.4 MB)
    const size_t needC = baseB + NE * 2 * 2;          // bf16 e + bf16 ehat  (~147.2 MB)

    if (ws_size >= needA) {
        run_net<float, float>(d_in, (float*)base, (float*)edge,
                              (float*)(edge + NE * 4), out, stream);
    } else if (ws_size >= needB) {
        run_net<float, __hip_bfloat16>(d_in, (float*)base, (float*)edge,
                                       (__hip_bfloat16*)(edge + NE * 4), out, stream);
    } else if (ws_size >= needC) {
        run_net<__hip_bfloat16, __hip_bfloat16>(d_in, (float*)base, (__hip_bfloat16*)edge,
                                                (__hip_bfloat16*)(edge + NE * 2), out, stream);
    } else {
        // diagnostic fallback: workspace still too small — emit zeros, don't fault
        hipMemsetAsync(d_out, 0, (size_t)out_size * sizeof(float), stream);
    }
}